// Round 14
// baseline (323.415 us; speedup 1.0000x reference)
//
#include <hip/hip_runtime.h>

// ---------------------------------------------------------------------------
// GGNN: 2x GatedGraphConv(GRUCell) + linear + softmax-attention pooling.
// N=100000 nodes, E=1600000 edges, D=64.
//
// Folds: segment_sum((h@C)[src]) == (segment_sum(h[src]))@C, and
// agg@W_ih^T == s@(C@W_ih^T).  Per layer: standalone node-parallel register
// gather of bf16 h rows (CSR by dst; 8-deep batched loads; ~4.4 TB/s
// effective on random rows -- near the cross-XCD fabric rate), emitting s
// as bf16; then a lean MFMA GEMM + GRU kernel at 8 waves/SIMD (VGPR=64
// fits exactly; R13's 4 waves/SIMD left barrier stalls uncovered).
//
// GEMM: operand-SWAPPED MFMA  D = W x Act^T  with gate-interleaved W rows
// (c' = ch*4+gate): each lane's f32x4 acc holds (r,z,i_n,h_n) of ONE
// (node,ch) -> GRU epilogue fully lane-parallel, zero cross-lane ops.
// B single bf16; A: s single bf16, h hi/lo 3-term (absmax ~1e-4 validated).
//
// CSR build (atomic-free, locality-clean): count -> scan2a/b -> scatter ->
// buildcsr.  Readout: MFMA tile GEMM with in-register softmax-attention.
// ---------------------------------------------------------------------------

typedef __attribute__((ext_vector_type(8))) short s8v;    // 8 bf16 (4 VGPRs)
typedef __attribute__((ext_vector_type(4))) float f32x4;  // MFMA accumulator

#define CSR_CAP 12288   // per-partition stage capacity (avg cnt ~4090)
#define HSTR 136        // A-hi LDS row stride (shorts): 128 + 8 pad
#define LSTR 72         // A-lo (h half) LDS row stride (shorts): 64 + 8 pad

__device__ __forceinline__ unsigned short f32_bf16_rn(float x) {
  unsigned u = __float_as_uint(x);
  u += 0x7FFF + ((u >> 16) & 1);
  return (unsigned short)(u >> 16);
}

__device__ __forceinline__ int wave_incl_scan(int v, int lane) {
#pragma unroll
  for (int d = 1; d < 64; d <<= 1) {
    int u = __shfl_up(v, d);
    if (lane >= d) v += u;
  }
  return v;
}

// Edge list may arrive as int32 or as int64 (we read low dwords).
__device__ __forceinline__ int detect_is64(const int* ei, int E) {
  int nz = 0;
  int lim = (E < 512) ? E : 512;
  for (int i = threadIdx.x; i < lim; i += blockDim.x)
    nz |= (ei[2 * i + 1] != 0);
  return __syncthreads_or(nz) ? 0 : 1;
}

__device__ __forceinline__ void load_edge(const int* ei, int E, int is64,
                                          int e, int& s, int& d) {
  if (is64) { s = ei[2 * e]; d = ei[2 * (E + e)]; }
  else      { s = ei[e];     d = ei[E + e]; }
}

// ---- pass 1: per-block LDS histogram over partitions (dst>>8) ----
__global__ __launch_bounds__(256) void count_kernel(
    const int* __restrict__ ei, int E,
    int* __restrict__ G, int P, int perBlk, int NB) {
  __shared__ int hist[512];
  int tid = threadIdx.x, b = blockIdx.x;
  for (int i = tid; i < 512; i += 256) hist[i] = 0;
  int is64 = detect_is64(ei, E);
  __syncthreads();
  int e0 = b * perBlk, e1 = min(e0 + perBlk, E);
  for (int e = e0 + tid; e < e1; e += 256) {
    int s, d; load_edge(ei, E, is64, e, s, d);
    atomicAdd(&hist[d >> 8], 1);
  }
  __syncthreads();
  for (int i = tid; i < P; i += 256) G[i * NB + b] = hist[i];
}

// ---- pass 2a: per-partition exclusive scan of per-block counts ----
__global__ __launch_bounds__(256) void scan2a(int* __restrict__ G,
                                              int* __restrict__ total, int NB) {
  __shared__ int wsum[4];
  int p = blockIdx.x, tid = threadIdx.x, lane = tid & 63, wv = tid >> 6;
  int v = G[p * NB + tid];
  int incl = wave_incl_scan(v, lane);
  if (lane == 63) wsum[wv] = incl;
  __syncthreads();
  if (tid == 0) {
    int a = wsum[0], b2 = wsum[1], c = wsum[2], d = wsum[3];
    total[p] = a + b2 + c + d;
    wsum[0] = 0; wsum[1] = a; wsum[2] = a + b2; wsum[3] = a + b2 + c;
  }
  __syncthreads();
  G[p * NB + tid] = incl - v + wsum[wv];
}

// ---- pass 2b: exclusive scan of partition totals -> partStart[P+1] ----
__global__ void scan2b(const int* __restrict__ total, int* __restrict__ partStart,
                       int P) {
  int lane = threadIdx.x;  // 64 threads
  int running = 0;
  for (int base = 0; base < P; base += 64) {
    int idx = base + lane;
    int v = (idx < P) ? total[idx] : 0;
    int incl = wave_incl_scan(v, lane);
    int tot = __shfl(incl, 63);
    if (idx < P) partStart[idx] = running + incl - v;
    running += tot;
  }
  if (lane == 0) partStart[P] = running;
}

// ---- pass 3: scatter packed edges into partition-major bucket ----
__global__ __launch_bounds__(256) void scatter_kernel(
    const int* __restrict__ ei, int E,
    const int* __restrict__ G, const int* __restrict__ partStart,
    int* __restrict__ bucket, int P, int perBlk, int NB) {
  __shared__ int cur[512];
  int tid = threadIdx.x, b = blockIdx.x;
  int is64 = detect_is64(ei, E);
  for (int i = tid; i < P; i += 256) cur[i] = partStart[i] + G[i * NB + b];
  __syncthreads();
  int e0 = b * perBlk, e1 = min(e0 + perBlk, E);
  for (int e = e0 + tid; e < e1; e += 256) {
    int s, d; load_edge(ei, E, is64, e, s, d);
    int pos = atomicAdd(&cur[d >> 8], 1);   // LDS atomic
    bucket[pos] = ((d & 255) << 17) | s;
  }
}

// ---- pass 4: per-partition CSR finalize (row_ptr + node-sorted col) ----
__global__ __launch_bounds__(256) void buildcsr_kernel(
    const int* __restrict__ partStart, const int* __restrict__ bucket,
    int* __restrict__ row_ptr, int* __restrict__ col, int N) {
  __shared__ int stage[CSR_CAP];
  __shared__ int hist[256];
  __shared__ int cur[256];
  __shared__ int wsum[4];
  int p = blockIdx.x, tid = threadIdx.x;
  int beg = partStart[p], end = partStart[p + 1];
  int cnt = end - beg;
  int base = p << 8;
  hist[tid] = 0;
  __syncthreads();
  bool staged = (cnt <= CSR_CAP);
  if (staged) {
    for (int i = tid; i < cnt; i += 256) {
      int v = bucket[beg + i];
      stage[i] = v;
      atomicAdd(&hist[(v >> 17) & 255], 1);
    }
  } else {
    for (int i = tid; i < cnt; i += 256)
      atomicAdd(&hist[(bucket[beg + i] >> 17) & 255], 1);
  }
  __syncthreads();
  int lane = tid & 63, wv = tid >> 6;
  int v = hist[tid];
  int incl = wave_incl_scan(v, lane);
  if (lane == 63) wsum[wv] = incl;
  __syncthreads();
  if (tid == 0) {
    int s0 = wsum[0], s1 = wsum[1], s2 = wsum[2];
    wsum[0] = 0; wsum[1] = s0; wsum[2] = s0 + s1; wsum[3] = s0 + s1 + s2;
  }
  __syncthreads();
  int excl = incl - v + wsum[wv];
  cur[tid] = beg + excl;
  if (base + tid < N) {
    if (tid == 0) row_ptr[base] = beg;
    row_ptr[base + tid + 1] = beg + excl + v;
  }
  __syncthreads();
  if (staged) {
    for (int i = tid; i < cnt; i += 256) {
      int v2 = stage[i];
      int pos = atomicAdd(&cur[(v2 >> 17) & 255], 1);
      col[pos] = v2 & 0x1FFFF;
    }
  } else {
    for (int i = tid; i < cnt; i += 256) {
      int v2 = bucket[beg + i];
      int pos = atomicAdd(&cur[(v2 >> 17) & 255], 1);
      col[pos] = v2 & 0x1FFFF;
    }
  }
}

// ---- weight prep: Bt (gru GEMM B, bf16, gate-interleaved cols c'=ch*4+g)
//      + Lt (lin_w, hi/lo) ----
__global__ void wprep_kernel(const float* __restrict__ conv_w,
                             const float* __restrict__ w_ih,
                             const float* __restrict__ whh,
                             const float* __restrict__ lin_w,
                             unsigned short* __restrict__ Bt,
                             unsigned short* __restrict__ Lt) {
  int idx = blockIdx.x * blockDim.x + threadIdx.x;
  if (idx < 65536) {
    int l = idx >> 15;
    int rr = idx & 32767;
    int cp = rr >> 7, p = rr & 127;
    int ch = cp >> 2, g = cp & 3;
    float val = 0.f;
    if (p < 64) {
      int j = (g == 0) ? ch : (g == 1) ? 64 + ch : (g == 2) ? 128 + ch : -1;
      if (j >= 0) {
        const float* C = conv_w + l * 4096 + p * 64;
        const float* W = w_ih + j * 64;
#pragma unroll 8
        for (int k = 0; k < 64; k++) val += C[k] * W[k];
      }
    } else {
      int q = p - 64;
      if (g == 0)      val = whh[ch * 64 + q];
      else if (g == 1) val = whh[(64 + ch) * 64 + q];
      else if (g == 3) val = whh[(128 + ch) * 64 + q];
    }
    Bt[(size_t)l * 32768 + (size_t)cp * 128 + p] = f32_bf16_rn(val);
  } else if (idx < 65536 + 4096) {
    int i2 = idx - 65536;
    float val = lin_w[i2];
    unsigned short hi = f32_bf16_rn(val);
    float fh = __uint_as_float((unsigned)hi << 16);
    unsigned short lo = f32_bf16_rn(val - fh);
    Lt[i2] = hi;
    Lt[4096 + i2] = lo;
  }
}

// ---- f32 -> bf16 row copy (for the gather source) ----
__global__ __launch_bounds__(256) void cvt16_kernel(
    const float* __restrict__ in, unsigned short* __restrict__ out, int n8) {
  int idx = blockIdx.x * blockDim.x + threadIdx.x;
  if (idx >= n8) return;
  const float4* p = (const float4*)(in + (size_t)idx * 8);
  float4 v0 = p[0], v1 = p[1];
  uint4 o;
  o.x = (unsigned)f32_bf16_rn(v0.x) | ((unsigned)f32_bf16_rn(v0.y) << 16);
  o.y = (unsigned)f32_bf16_rn(v0.z) | ((unsigned)f32_bf16_rn(v0.w) << 16);
  o.z = (unsigned)f32_bf16_rn(v1.x) | ((unsigned)f32_bf16_rn(v1.y) << 16);
  o.w = (unsigned)f32_bf16_rn(v1.z) | ((unsigned)f32_bf16_rn(v1.w) << 16);
  *(uint4*)(out + (size_t)idx * 8) = o;
}

__device__ __forceinline__ void acc_u2(unsigned rx, unsigned ry, float4& a) {
  a.x += __uint_as_float(rx << 16);
  a.y += __uint_as_float(rx & 0xFFFF0000u);
  a.z += __uint_as_float(ry << 16);
  a.w += __uint_as_float(ry & 0xFFFF0000u);
}

// s[n,:] = sum over in-edges of bf16 h[src,:] (f32 accumulate, bf16 out).
// One wave per node; lane = (edge-group 0..3) x (bf16x4 chunk 0..15).
// 8-deep explicit load batch per group (covers degree<=32; mean group
// degree = 4).  Invalid slots re-load the group's first row (L1-hit).
__global__ __launch_bounds__(256) void gather_kernel(
    const unsigned short* __restrict__ hb, const int* __restrict__ row_ptr,
    const int* __restrict__ col, unsigned short* __restrict__ sout,
    int N, int Em1) {
  int gt = blockIdx.x * blockDim.x + threadIdx.x;
  int n = gt >> 6, lane = gt & 63;
  if (n >= N) return;
  int grp = lane >> 4, q = lane & 15;
  int beg = row_ptr[n], end = row_ptr[n + 1];
  float4 acc = make_float4(0.f, 0.f, 0.f, 0.f);

  {  // ---- 8-deep batched head: edges beg+grp+4*i, i in [0,8) ----
    int safe0 = min(beg, Em1);
    uint2 r[8];
    int idx[8];
#pragma unroll
    for (int i = 0; i < 8; i++) {
      int ee = beg + grp + 4 * i;
      idx[i] = (ee < end) ? ee : -1;
      int ci = (idx[i] >= 0) ? ee : safe0;
      int s = col[ci];
      r[i] = *(const uint2*)(hb + (size_t)s * 64 + q * 4);
    }
#pragma unroll
    for (int i = 0; i < 8; i++)
      if (idx[i] >= 0) acc_u2(r[i].x, r[i].y, acc);
  }
  // ---- rare tail: degree > 32 ----
  for (int ee = beg + grp + 32; ee < end; ee += 4) {
    int s = col[ee];
    uint2 r = *(const uint2*)(hb + (size_t)s * 64 + q * 4);
    acc_u2(r.x, r.y, acc);
  }

#pragma unroll
  for (int off = 16; off <= 32; off <<= 1) {
    acc.x += __shfl_xor(acc.x, off);
    acc.y += __shfl_xor(acc.y, off);
    acc.z += __shfl_xor(acc.z, off);
    acc.w += __shfl_xor(acc.w, off);
  }
  if (grp == 0) {
    uint2 o;
    o.x = (unsigned)f32_bf16_rn(acc.x) | ((unsigned)f32_bf16_rn(acc.y) << 16);
    o.y = (unsigned)f32_bf16_rn(acc.z) | ((unsigned)f32_bf16_rn(acc.w) << 16);
    *(uint2*)(sout + (size_t)n * 64 + q * 4) = o;
  }
}

// MFMA GEMM + GRU gates, operand-swapped: D = W x Act^T.
// 512 threads (8 waves), tile = 64 nodes, 8 waves/SIMD (VGPR=64 fits
// exactly -> 4 blocks/CU; R13's 4 waves/SIMD left barrier stalls
// uncovered).  Wave w owns c' rows [32w,32w+32) x all 4 node-subtiles.
// Output: col=node(l15), row=c' -> lane's f32x4 acc = (r,z,in,hn) of
// (node = 16m+l15, ch = 8w+4ct+q).  Epilogue lane-parallel, no shfl.
__global__ __launch_bounds__(512, 8) void gemm_gru_kernel(
    const unsigned short* __restrict__ s16, const float* __restrict__ hin,
    float* __restrict__ hout, unsigned short* __restrict__ hb16,
    const unsigned short* __restrict__ bt,
    const float* __restrict__ b_ih, const float* __restrict__ b_hh,
    int N, int ntiles, int wb16) {
  __shared__ short Ahi[64 * HSTR];   // [s(0:64) || h(64:128)] hi
  __shared__ short Alo[64 * LSTR];   // h lo only
  const int tid = threadIdx.x;
  const int lane = tid & 63, w = tid >> 6;
  const int l15 = lane & 15, ko = (lane >> 4) * 8;
  const int q = lane >> 4;

  // W fragments (A-operand of swapped MFMA): lane holds W[c'=32w+16ct+l15][k].
  s8v Bf[2][4];
#pragma unroll
  for (int ct = 0; ct < 2; ct++)
#pragma unroll
    for (int kk = 0; kk < 4; kk++)
      Bf[ct][kk] = *(const s8v*)(bt + (size_t)(32 * w + 16 * ct + l15) * 128 +
                                 kk * 32 + ko);

  // This lane's channels: ct=0 -> 8w+q, ct=1 -> 8w+4+q.
  const int ch0 = 8 * w + q, ch1 = ch0 + 4;
  const float br0 = b_ih[ch0] + b_hh[ch0], br1 = b_ih[ch1] + b_hh[ch1];
  const float bz0 = b_ih[64 + ch0] + b_hh[64 + ch0], bz1 = b_ih[64 + ch1] + b_hh[64 + ch1];
  const float bi0 = b_ih[128 + ch0], bi1 = b_ih[128 + ch1];
  const float bn0 = b_hh[128 + ch0], bn1 = b_hh[128 + ch1];

  const int g = tid >> 3, qc = tid & 7;   // staging: node-in-tile, ch-octet

  for (int tile = blockIdx.x; tile < ntiles; tile += gridDim.x) {
    const int nb = tile * 64;
    const int node = nb + g;
    {  // ---- s staging: raw bf16 copy ----
      uint4 sv = make_uint4(0, 0, 0, 0);
      if (node < N) sv = *(const uint4*)(s16 + (size_t)node * 64 + qc * 8);
      *(uint4*)&Ahi[g * HSTR + qc * 8] = sv;
    }
    {  // ---- h staging: hi/lo split, 8 ch ----
      f32x4 v0 = (f32x4)(0.f), v1 = (f32x4)(0.f);
      if (node < N) {
        v0 = *(const f32x4*)(hin + (size_t)node * 64 + qc * 8);
        v1 = *(const f32x4*)(hin + (size_t)node * 64 + qc * 8 + 4);
      }
      s8v hv, lv;
#pragma unroll
      for (int i = 0; i < 8; i++) {
        float x = (i < 4) ? v0[i] : v1[i - 4];
        unsigned short hb = f32_bf16_rn(x);
        hv[i] = (short)hb;
        lv[i] = (short)f32_bf16_rn(x - __uint_as_float((unsigned)hb << 16));
      }
      *(s8v*)&Ahi[g * HSTR + 64 + qc * 8] = hv;
      *(s8v*)&Alo[g * LSTR + qc * 8] = lv;
    }
    __syncthreads();

    f32x4 acc[4][2];
#pragma unroll
    for (int m = 0; m < 4; m++)
#pragma unroll
      for (int ct = 0; ct < 2; ct++) acc[m][ct] = (f32x4)(0.f);

#pragma unroll
    for (int m = 0; m < 4; m++) {
      const short* arh = &Ahi[(16 * m + l15) * HSTR + ko];
      const short* arl = &Alo[(16 * m + l15) * LSTR + ko];
#pragma unroll
      for (int kk = 0; kk < 4; kk++) {
        s8v a_h = *(const s8v*)(arh + kk * 32);
#pragma unroll
        for (int ct = 0; ct < 2; ct++)   // SWAPPED operands: W is arg0
          acc[m][ct] = __builtin_amdgcn_mfma_f32_16x16x32_bf16(Bf[ct][kk], a_h, acc[m][ct], 0, 0, 0);
        if (kk >= 2) {
          s8v a_l = *(const s8v*)(arl + (kk - 2) * 32);
#pragma unroll
          for (int ct = 0; ct < 2; ct++)
            acc[m][ct] = __builtin_amdgcn_mfma_f32_16x16x32_bf16(Bf[ct][kk], a_l, acc[m][ct], 0, 0, 0);
        }
      }
    }

    // ---- GRU gate epilogue: fully lane-parallel, acc = (r,z,in,hn) ----
#pragma unroll
    for (int m = 0; m < 4; m++) {
      int loc = 16 * m + l15;
      int nd = nb + loc;
      if (nd < N) {
#pragma unroll
        for (int ct = 0; ct < 2; ct++) {
          int ch = ct ? ch1 : ch0;
          unsigned hi = (unsigned short)Ahi[loc * HSTR + 64 + ch];
          unsigned lo = (unsigned short)Alo[loc * LSTR + ch];
          float hold = __uint_as_float(hi << 16) + __uint_as_float(lo << 16);
          float rr = 1.f / (1.f + __expf(-(acc[m][ct][0] + (ct ? br1 : br0))));
          float zz = 1.f / (1.f + __expf(-(acc[m][ct][1] + (ct ? bz1 : bz0))));
          float narg = acc[m][ct][2] + (ct ? bi1 : bi0) +
                       rr * (acc[m][ct][3] + (ct ? bn1 : bn0));
          narg = fminf(fmaxf(narg, -15.f), 15.f);
          float t = __expf(2.f * narg);
          float nn = (t - 1.f) / (t + 1.f);
          float hv = (1.f - zz) * nn + zz * hold;
          hout[(size_t)nd * 64 + ch] = hv;
          if (wb16) hb16[(size_t)nd * 64 + ch] = f32_bf16_rn(hv);
        }
      }
    }
    __syncthreads();  // LDS (epilogue reads) safe before next staging
  }
}

// Readout via MFMA: y = relu(h)@lin_w^T + lin_b; t = y.attn_w + attn_b;
// softmax-attention partial sums accumulated in registers across tiles.
__global__ __launch_bounds__(256, 2) void final_mfma(
    const float* __restrict__ h, const unsigned short* __restrict__ Lt,
    const float* __restrict__ lin_b, const float* __restrict__ attn_w,
    const float* __restrict__ attn_b, float* __restrict__ partials,
    int N, int ntiles) {
  __shared__ short Alds[2 * 64 * 72];   // hi then lo, stride 72 shorts
  __shared__ float red[4][64];
  __shared__ float pl[64];
  const int tid = threadIdx.x;
  const int lane = tid & 63, w = tid >> 6;
  const int l15 = lane & 15, ko = (lane >> 4) * 8;
  const int q = lane >> 4;

  s8v Lh[2], Ll[2];
  const int col = 16 * w + l15;
#pragma unroll
  for (int kk = 0; kk < 2; kk++) {
    Lh[kk] = *(const s8v*)(Lt + (size_t)col * 64 + kk * 32 + ko);
    Ll[kk] = *(const s8v*)(Lt + 4096 + (size_t)col * 64 + kk * 32 + ko);
  }
  const float lb = lin_b[col];
  const float aw = attn_w[col];
  const float ab = attn_b[0];
  const int sr = tid >> 2, part = tid & 3;

  float accS = 0.f;
  float accY = 0.f;

  for (int tile = blockIdx.x; tile < ntiles; tile += gridDim.x) {
    const int nb = tile * 64;
    {  // ---- stage relu(h) as bf16 hi/lo ----
      int node = nb + sr;
      f32x4 v[4];
      if (node < N) {
#pragma unroll
        for (int i = 0; i < 4; i++)
          v[i] = *(const f32x4*)(h + (size_t)node * 64 + part * 16 + 4 * i);
      } else {
#pragma unroll
        for (int i = 0; i < 4; i++) v[i] = (f32x4)(0.f);
      }
      short* ah = &Alds[sr * 72 + part * 16];
#pragma unroll
      for (int i2 = 0; i2 < 2; i2++) {
        s8v hv, lv;
#pragma unroll
        for (int e = 0; e < 8; e++) {
          float x = fmaxf(v[i2 * 2 + (e >> 2)][e & 3], 0.f);
          unsigned short hb = f32_bf16_rn(x);
          float fh = __uint_as_float((unsigned)hb << 16);
          unsigned short lo2 = f32_bf16_rn(x - fh);
          hv[e] = (short)hb;
          lv[e] = (short)lo2;
        }
        *(s8v*)(ah + i2 * 8) = hv;
        *(s8v*)(ah + 64 * 72 + i2 * 8) = lv;
      }
    }
    __syncthreads();

    f32x4 acc[4];
#pragma unroll
    for (int m = 0; m < 4; m++) acc[m] = (f32x4)(0.f);
#pragma unroll
    for (int m = 0; m < 4; m++) {
      const short* arow = &Alds[(16 * m + l15) * 72 + ko];
#pragma unroll
      for (int kk = 0; kk < 2; kk++) {
        s8v a_h = *(const s8v*)(arow + kk * 32);
        s8v a_l = *(const s8v*)(arow + 64 * 72 + kk * 32);
        acc[m] = __builtin_amdgcn_mfma_f32_16x16x32_bf16(a_h, Lh[kk], acc[m], 0, 0, 0);
        acc[m] = __builtin_amdgcn_mfma_f32_16x16x32_bf16(a_h, Ll[kk], acc[m], 0, 0, 0);
        acc[m] = __builtin_amdgcn_mfma_f32_16x16x32_bf16(a_l, Lh[kk], acc[m], 0, 0, 0);
      }
    }
    __syncthreads();

    float cc[4][4];
#pragma unroll
    for (int m = 0; m < 4; m++)
#pragma unroll
      for (int g = 0; g < 4; g++) cc[m][g] = (acc[m][g] + lb) * aw;
#pragma unroll
    for (int off = 1; off <= 8; off <<= 1)
#pragma unroll
      for (int m = 0; m < 4; m++)
#pragma unroll
        for (int g = 0; g < 4; g++) cc[m][g] += __shfl_xor(cc[m][g], off);
    if (l15 == 0) {
#pragma unroll
      for (int m = 0; m < 4; m++)
#pragma unroll
        for (int g = 0; g < 4; g++) red[w][16 * m + 4 * q + g] = cc[m][g];
    }
    __syncthreads();
    if (tid < 64) {
      float t = red[0][tid] + red[1][tid] + red[2][tid] + red[3][tid] + ab;
      float p = (nb + tid < N) ? __expf(t) : 0.f;
      pl[tid] = p;
      accS += p;
    }
    __syncthreads();
#pragma unroll
    for (int m = 0; m < 4; m++)
#pragma unroll
      for (int g = 0; g < 4; g++)
        accY += pl[16 * m + 4 * q + g] * (acc[m][g] + lb);
  }

  accY += __shfl_xor(accY, 16);
  accY += __shfl_xor(accY, 32);
  if (lane < 16) partials[(size_t)blockIdx.x * 66 + 16 * w + lane] = accY;
  if (w == 0) {
    float s = accS;
#pragma unroll
    for (int off = 1; off < 64; off <<= 1) s += __shfl_xor(s, off);
    if (lane == 0) partials[(size_t)blockIdx.x * 66 + 64] = s;
  }
}

__global__ void final_p2(const float* __restrict__ partials,
                         float* __restrict__ out, int nb) {
  __shared__ float red[16][65];
  int tid = threadIdx.x;  // 1024
  int j = tid & 63, grp = tid >> 6;
  float sy = 0.f, ss = 0.f;
  for (int b = grp; b < nb; b += 16) {
    sy += partials[b * 66 + j];
    if (j == 0) ss += partials[b * 66 + 64];
  }
  red[grp][j] = sy;
  if (j == 0) red[grp][64] = ss;
  __syncthreads();
  if (tid < 64) {
    float Y = 0.f, S = 0.f;
#pragma unroll
    for (int i = 0; i < 16; i++) { Y += red[i][tid]; S += red[i][64]; }
    out[tid] = Y / S;
  }
}

extern "C" void kernel_launch(void* const* d_in, const int* in_sizes, int n_in,
                              void* d_out, int out_size, void* d_ws, size_t ws_size,
                              hipStream_t stream) {
  const float* x       = (const float*)d_in[0];
  const int*   ei      = (const int*)d_in[1];
  const float* conv_w  = (const float*)d_in[2];
  const float* gw_ih   = (const float*)d_in[3];
  const float* gw_hh   = (const float*)d_in[4];
  const float* gb_ih   = (const float*)d_in[5];
  const float* gb_hh   = (const float*)d_in[6];
  const float* lin_w   = (const float*)d_in[7];
  const float* lin_b   = (const float*)d_in[8];
  const float* attn_w  = (const float*)d_in[9];
  const float* attn_b  = (const float*)d_in[10];
  float* out = (float*)d_out;

  const int N = in_sizes[0] / 64;
  const int E = in_sizes[1] / 2;
  const int P  = (N + 255) >> 8;   // 256-node partitions
  const int NB = 256;              // binning blocks
  const int perBlk = (E + NB - 1) / NB;

  char* ws = (char*)d_ws;
  size_t off = 0;
  auto alloc = [&](size_t bytes) {
    void* p = ws + off;
    off = (off + bytes + 255) & ~(size_t)255;
    return p;
  };
  int*   G         = (int*)alloc((size_t)P * NB * 4);
  int*   total     = (int*)alloc((size_t)P * 4);
  int*   partStart = (int*)alloc((size_t)(P + 1) * 4);
  int*   bucket    = (int*)alloc((size_t)E * 4);
  int*   row_ptr   = (int*)alloc((size_t)(N + 1) * 4);
  int*   colb      = (int*)alloc((size_t)E * 4);
  unsigned short* Bt  = (unsigned short*)alloc(2 * 256 * 128 * 2);
  unsigned short* Lt  = (unsigned short*)alloc(2 * 4096 * 2);
  unsigned short* b16x = (unsigned short*)alloc((size_t)N * 64 * 2);  // x bf16
  unsigned short* b16h = (unsigned short*)alloc((size_t)N * 64 * 2);  // h1 bf16
  unsigned short* s16  = (unsigned short*)alloc((size_t)N * 64 * 2);  // gathered s
  float* hbuf      = (float*)alloc((size_t)N * 64 * 4);
  float* partials  = (float*)alloc(1024 * 66 * 4);
  if (off > ws_size) return;  // ws too small: leave output poisoned

  count_kernel<<<NB, 256, 0, stream>>>(ei, E, G, P, perBlk, NB);
  scan2a<<<P, 256, 0, stream>>>(G, total, NB);
  scan2b<<<1, 64, 0, stream>>>(total, partStart, P);
  scatter_kernel<<<NB, 256, 0, stream>>>(ei, E, G, partStart, bucket, P, perBlk, NB);
  buildcsr_kernel<<<P, 256, 0, stream>>>(partStart, bucket, row_ptr, colb, N);
  wprep_kernel<<<(65536 + 4096 + 255) / 256, 256, 0, stream>>>(conv_w, gw_ih, gw_hh,
                                                               lin_w, Bt, Lt);
  int n8 = (N * 64) / 8;
  cvt16_kernel<<<(n8 + 255) / 256, 256, 0, stream>>>(x, b16x, n8);

  int gb = (N * 64 + 255) / 256;       // gather: 1 wave per node
  int ntiles = (N + 63) / 64;
  // layer 0: gather from x-bf16; h = x; gemm emits h1 bf16 into b16h
  gather_kernel<<<gb, 256, 0, stream>>>(b16x, row_ptr, colb, s16, N, E - 1);
  gemm_gru_kernel<<<1024, 512, 0, stream>>>(s16, x, hbuf, b16h, Bt,
                                            gb_ih, gb_hh, N, ntiles, 1);
  // layer 1: gather from h1-bf16; h = hbuf (in-place update)
  gather_kernel<<<gb, 256, 0, stream>>>(b16h, row_ptr, colb, s16, N, E - 1);
  gemm_gru_kernel<<<1024, 512, 0, stream>>>(s16, hbuf, hbuf, b16h, Bt + 32768,
                                            gb_ih, gb_hh, N, ntiles, 0);
  // readout
  final_mfma<<<512, 256, 0, stream>>>(hbuf, Lt, lin_b, attn_w, attn_b, partials, N, ntiles);
  final_p2<<<1, 1024, 0, stream>>>(partials, out, 512);
}

// Round 15
// 233.463 us; speedup vs baseline: 1.3853x; 1.3853x over previous
//
#include <hip/hip_runtime.h>

// ---------------------------------------------------------------------------
// GGNN: 2x GatedGraphConv(GRUCell) + linear + softmax-attention pooling.
// N=100000 nodes, E=1600000 edges, D=64.
//
// Folds: segment_sum((h@C)[src]) == (segment_sum(h[src]))@C, and
// agg@W_ih^T == s@(C@W_ih^T).  Per layer: standalone node-parallel register
// gather of bf16 h rows (CSR by dst; 8-deep batched loads; ~4.4 TB/s
// effective on random rows), emitting s as bf16; then a lean MFMA GEMM +
// GRU kernel.  gemm: launch_bounds(512,4) keeps VGPR=64 (R14's (512,8)
// forced VGPR=32 -> 300MB spill traffic); grid=1024 gives 4 blocks/CU
// co-residency (R14 confirmed 72% occupancy at this grid).
//
// GEMM: operand-SWAPPED MFMA  D = W x Act^T  with gate-interleaved W rows
// (c' = ch*4+gate): each lane's f32x4 acc holds (r,z,i_n,h_n) of ONE
// (node,ch) -> GRU epilogue fully lane-parallel, zero cross-lane ops.
// B single bf16; A: s single bf16, h hi/lo 3-term (absmax ~1e-4 validated).
//
// CSR build (atomic-free, locality-clean): count -> scan2a/b -> scatter ->
// buildcsr.  Readout: MFMA tile GEMM with in-register softmax-attention.
// ---------------------------------------------------------------------------

typedef __attribute__((ext_vector_type(8))) short s8v;    // 8 bf16 (4 VGPRs)
typedef __attribute__((ext_vector_type(4))) float f32x4;  // MFMA accumulator

#define CSR_CAP 12288   // per-partition stage capacity (avg cnt ~4090)
#define HSTR 136        // A-hi LDS row stride (shorts): 128 + 8 pad
#define LSTR 72         // A-lo (h half) LDS row stride (shorts): 64 + 8 pad

__device__ __forceinline__ unsigned short f32_bf16_rn(float x) {
  unsigned u = __float_as_uint(x);
  u += 0x7FFF + ((u >> 16) & 1);
  return (unsigned short)(u >> 16);
}

__device__ __forceinline__ int wave_incl_scan(int v, int lane) {
#pragma unroll
  for (int d = 1; d < 64; d <<= 1) {
    int u = __shfl_up(v, d);
    if (lane >= d) v += u;
  }
  return v;
}

// Edge list may arrive as int32 or as int64 (we read low dwords).
__device__ __forceinline__ int detect_is64(const int* ei, int E) {
  int nz = 0;
  int lim = (E < 512) ? E : 512;
  for (int i = threadIdx.x; i < lim; i += blockDim.x)
    nz |= (ei[2 * i + 1] != 0);
  return __syncthreads_or(nz) ? 0 : 1;
}

__device__ __forceinline__ void load_edge(const int* ei, int E, int is64,
                                          int e, int& s, int& d) {
  if (is64) { s = ei[2 * e]; d = ei[2 * (E + e)]; }
  else      { s = ei[e];     d = ei[E + e]; }
}

// ---- pass 1: per-block LDS histogram over partitions (dst>>8) ----
__global__ __launch_bounds__(256) void count_kernel(
    const int* __restrict__ ei, int E,
    int* __restrict__ G, int P, int perBlk, int NB) {
  __shared__ int hist[512];
  int tid = threadIdx.x, b = blockIdx.x;
  for (int i = tid; i < 512; i += 256) hist[i] = 0;
  int is64 = detect_is64(ei, E);
  __syncthreads();
  int e0 = b * perBlk, e1 = min(e0 + perBlk, E);
  for (int e = e0 + tid; e < e1; e += 256) {
    int s, d; load_edge(ei, E, is64, e, s, d);
    atomicAdd(&hist[d >> 8], 1);
  }
  __syncthreads();
  for (int i = tid; i < P; i += 256) G[i * NB + b] = hist[i];
}

// ---- pass 2a: per-partition exclusive scan of per-block counts ----
__global__ __launch_bounds__(256) void scan2a(int* __restrict__ G,
                                              int* __restrict__ total, int NB) {
  __shared__ int wsum[4];
  int p = blockIdx.x, tid = threadIdx.x, lane = tid & 63, wv = tid >> 6;
  int v = G[p * NB + tid];
  int incl = wave_incl_scan(v, lane);
  if (lane == 63) wsum[wv] = incl;
  __syncthreads();
  if (tid == 0) {
    int a = wsum[0], b2 = wsum[1], c = wsum[2], d = wsum[3];
    total[p] = a + b2 + c + d;
    wsum[0] = 0; wsum[1] = a; wsum[2] = a + b2; wsum[3] = a + b2 + c;
  }
  __syncthreads();
  G[p * NB + tid] = incl - v + wsum[wv];
}

// ---- pass 2b: exclusive scan of partition totals -> partStart[P+1] ----
__global__ void scan2b(const int* __restrict__ total, int* __restrict__ partStart,
                       int P) {
  int lane = threadIdx.x;  // 64 threads
  int running = 0;
  for (int base = 0; base < P; base += 64) {
    int idx = base + lane;
    int v = (idx < P) ? total[idx] : 0;
    int incl = wave_incl_scan(v, lane);
    int tot = __shfl(incl, 63);
    if (idx < P) partStart[idx] = running + incl - v;
    running += tot;
  }
  if (lane == 0) partStart[P] = running;
}

// ---- pass 3: scatter packed edges into partition-major bucket ----
__global__ __launch_bounds__(256) void scatter_kernel(
    const int* __restrict__ ei, int E,
    const int* __restrict__ G, const int* __restrict__ partStart,
    int* __restrict__ bucket, int P, int perBlk, int NB) {
  __shared__ int cur[512];
  int tid = threadIdx.x, b = blockIdx.x;
  int is64 = detect_is64(ei, E);
  for (int i = tid; i < P; i += 256) cur[i] = partStart[i] + G[i * NB + b];
  __syncthreads();
  int e0 = b * perBlk, e1 = min(e0 + perBlk, E);
  for (int e = e0 + tid; e < e1; e += 256) {
    int s, d; load_edge(ei, E, is64, e, s, d);
    int pos = atomicAdd(&cur[d >> 8], 1);   // LDS atomic
    bucket[pos] = ((d & 255) << 17) | s;
  }
}

// ---- pass 4: per-partition CSR finalize (row_ptr + node-sorted col) ----
__global__ __launch_bounds__(256) void buildcsr_kernel(
    const int* __restrict__ partStart, const int* __restrict__ bucket,
    int* __restrict__ row_ptr, int* __restrict__ col, int N) {
  __shared__ int stage[CSR_CAP];
  __shared__ int hist[256];
  __shared__ int cur[256];
  __shared__ int wsum[4];
  int p = blockIdx.x, tid = threadIdx.x;
  int beg = partStart[p], end = partStart[p + 1];
  int cnt = end - beg;
  int base = p << 8;
  hist[tid] = 0;
  __syncthreads();
  bool staged = (cnt <= CSR_CAP);
  if (staged) {
    for (int i = tid; i < cnt; i += 256) {
      int v = bucket[beg + i];
      stage[i] = v;
      atomicAdd(&hist[(v >> 17) & 255], 1);
    }
  } else {
    for (int i = tid; i < cnt; i += 256)
      atomicAdd(&hist[(bucket[beg + i] >> 17) & 255], 1);
  }
  __syncthreads();
  int lane = tid & 63, wv = tid >> 6;
  int v = hist[tid];
  int incl = wave_incl_scan(v, lane);
  if (lane == 63) wsum[wv] = incl;
  __syncthreads();
  if (tid == 0) {
    int s0 = wsum[0], s1 = wsum[1], s2 = wsum[2];
    wsum[0] = 0; wsum[1] = s0; wsum[2] = s0 + s1; wsum[3] = s0 + s1 + s2;
  }
  __syncthreads();
  int excl = incl - v + wsum[wv];
  cur[tid] = beg + excl;
  if (base + tid < N) {
    if (tid == 0) row_ptr[base] = beg;
    row_ptr[base + tid + 1] = beg + excl + v;
  }
  __syncthreads();
  if (staged) {
    for (int i = tid; i < cnt; i += 256) {
      int v2 = stage[i];
      int pos = atomicAdd(&cur[(v2 >> 17) & 255], 1);
      col[pos] = v2 & 0x1FFFF;
    }
  } else {
    for (int i = tid; i < cnt; i += 256) {
      int v2 = bucket[beg + i];
      int pos = atomicAdd(&cur[(v2 >> 17) & 255], 1);
      col[pos] = v2 & 0x1FFFF;
    }
  }
}

// ---- weight prep: Bt (gru GEMM B, bf16, gate-interleaved cols c'=ch*4+g)
//      + Lt (lin_w, hi/lo) ----
__global__ void wprep_kernel(const float* __restrict__ conv_w,
                             const float* __restrict__ w_ih,
                             const float* __restrict__ whh,
                             const float* __restrict__ lin_w,
                             unsigned short* __restrict__ Bt,
                             unsigned short* __restrict__ Lt) {
  int idx = blockIdx.x * blockDim.x + threadIdx.x;
  if (idx < 65536) {
    int l = idx >> 15;
    int rr = idx & 32767;
    int cp = rr >> 7, p = rr & 127;
    int ch = cp >> 2, g = cp & 3;
    float val = 0.f;
    if (p < 64) {
      int j = (g == 0) ? ch : (g == 1) ? 64 + ch : (g == 2) ? 128 + ch : -1;
      if (j >= 0) {
        const float* C = conv_w + l * 4096 + p * 64;
        const float* W = w_ih + j * 64;
#pragma unroll 8
        for (int k = 0; k < 64; k++) val += C[k] * W[k];
      }
    } else {
      int q = p - 64;
      if (g == 0)      val = whh[ch * 64 + q];
      else if (g == 1) val = whh[(64 + ch) * 64 + q];
      else if (g == 3) val = whh[(128 + ch) * 64 + q];
    }
    Bt[(size_t)l * 32768 + (size_t)cp * 128 + p] = f32_bf16_rn(val);
  } else if (idx < 65536 + 4096) {
    int i2 = idx - 65536;
    float val = lin_w[i2];
    unsigned short hi = f32_bf16_rn(val);
    float fh = __uint_as_float((unsigned)hi << 16);
    unsigned short lo = f32_bf16_rn(val - fh);
    Lt[i2] = hi;
    Lt[4096 + i2] = lo;
  }
}

// ---- f32 -> bf16 row copy (for the gather source) ----
__global__ __launch_bounds__(256) void cvt16_kernel(
    const float* __restrict__ in, unsigned short* __restrict__ out, int n8) {
  int idx = blockIdx.x * blockDim.x + threadIdx.x;
  if (idx >= n8) return;
  const float4* p = (const float4*)(in + (size_t)idx * 8);
  float4 v0 = p[0], v1 = p[1];
  uint4 o;
  o.x = (unsigned)f32_bf16_rn(v0.x) | ((unsigned)f32_bf16_rn(v0.y) << 16);
  o.y = (unsigned)f32_bf16_rn(v0.z) | ((unsigned)f32_bf16_rn(v0.w) << 16);
  o.z = (unsigned)f32_bf16_rn(v1.x) | ((unsigned)f32_bf16_rn(v1.y) << 16);
  o.w = (unsigned)f32_bf16_rn(v1.z) | ((unsigned)f32_bf16_rn(v1.w) << 16);
  *(uint4*)(out + (size_t)idx * 8) = o;
}

__device__ __forceinline__ void acc_u2(unsigned rx, unsigned ry, float4& a) {
  a.x += __uint_as_float(rx << 16);
  a.y += __uint_as_float(rx & 0xFFFF0000u);
  a.z += __uint_as_float(ry << 16);
  a.w += __uint_as_float(ry & 0xFFFF0000u);
}

// s[n,:] = sum over in-edges of bf16 h[src,:] (f32 accumulate, bf16 out).
// One wave per node; lane = (edge-group 0..3) x (bf16x4 chunk 0..15).
// 8-deep explicit load batch per group (covers degree<=32; mean group
// degree = 4).  Invalid slots re-load the group's first row (L1-hit).
__global__ __launch_bounds__(256) void gather_kernel(
    const unsigned short* __restrict__ hb, const int* __restrict__ row_ptr,
    const int* __restrict__ col, unsigned short* __restrict__ sout,
    int N, int Em1) {
  int gt = blockIdx.x * blockDim.x + threadIdx.x;
  int n = gt >> 6, lane = gt & 63;
  if (n >= N) return;
  int grp = lane >> 4, q = lane & 15;
  int beg = row_ptr[n], end = row_ptr[n + 1];
  float4 acc = make_float4(0.f, 0.f, 0.f, 0.f);

  {  // ---- 8-deep batched head: edges beg+grp+4*i, i in [0,8) ----
    int safe0 = min(beg, Em1);
    uint2 r[8];
    int idx[8];
#pragma unroll
    for (int i = 0; i < 8; i++) {
      int ee = beg + grp + 4 * i;
      idx[i] = (ee < end) ? ee : -1;
      int ci = (idx[i] >= 0) ? ee : safe0;
      int s = col[ci];
      r[i] = *(const uint2*)(hb + (size_t)s * 64 + q * 4);
    }
#pragma unroll
    for (int i = 0; i < 8; i++)
      if (idx[i] >= 0) acc_u2(r[i].x, r[i].y, acc);
  }
  // ---- rare tail: degree > 32 ----
  for (int ee = beg + grp + 32; ee < end; ee += 4) {
    int s = col[ee];
    uint2 r = *(const uint2*)(hb + (size_t)s * 64 + q * 4);
    acc_u2(r.x, r.y, acc);
  }

#pragma unroll
  for (int off = 16; off <= 32; off <<= 1) {
    acc.x += __shfl_xor(acc.x, off);
    acc.y += __shfl_xor(acc.y, off);
    acc.z += __shfl_xor(acc.z, off);
    acc.w += __shfl_xor(acc.w, off);
  }
  if (grp == 0) {
    uint2 o;
    o.x = (unsigned)f32_bf16_rn(acc.x) | ((unsigned)f32_bf16_rn(acc.y) << 16);
    o.y = (unsigned)f32_bf16_rn(acc.z) | ((unsigned)f32_bf16_rn(acc.w) << 16);
    *(uint2*)(sout + (size_t)n * 64 + q * 4) = o;
  }
}

// MFMA GEMM + GRU gates, operand-swapped: D = W x Act^T.
// 512 threads (8 waves), tile = 64 nodes.  launch_bounds(512,4): natural
// VGPR=64 (no spill; (512,8) forced VGPR=32 + 300MB spill traffic, R14).
// VGPR=64 + LDS 26.6KB permit 4 blocks/CU; grid=1024 realizes it.
// Wave w owns c' rows [32w,32w+32) x all 4 node-subtiles.  Output:
// col=node(l15), row=c' -> lane's f32x4 acc = (r,z,in,hn) of
// (node = 16m+l15, ch = 8w+4ct+q).  Epilogue lane-parallel, no shfl.
__global__ __launch_bounds__(512, 4) void gemm_gru_kernel(
    const unsigned short* __restrict__ s16, const float* __restrict__ hin,
    float* __restrict__ hout, unsigned short* __restrict__ hb16,
    const unsigned short* __restrict__ bt,
    const float* __restrict__ b_ih, const float* __restrict__ b_hh,
    int N, int ntiles, int wb16) {
  __shared__ short Ahi[64 * HSTR];   // [s(0:64) || h(64:128)] hi
  __shared__ short Alo[64 * LSTR];   // h lo only
  const int tid = threadIdx.x;
  const int lane = tid & 63, w = tid >> 6;
  const int l15 = lane & 15, ko = (lane >> 4) * 8;
  const int q = lane >> 4;

  // W fragments (A-operand of swapped MFMA): lane holds W[c'=32w+16ct+l15][k].
  s8v Bf[2][4];
#pragma unroll
  for (int ct = 0; ct < 2; ct++)
#pragma unroll
    for (int kk = 0; kk < 4; kk++)
      Bf[ct][kk] = *(const s8v*)(bt + (size_t)(32 * w + 16 * ct + l15) * 128 +
                                 kk * 32 + ko);

  // This lane's channels: ct=0 -> 8w+q, ct=1 -> 8w+4+q.
  const int ch0 = 8 * w + q, ch1 = ch0 + 4;
  const float br0 = b_ih[ch0] + b_hh[ch0], br1 = b_ih[ch1] + b_hh[ch1];
  const float bz0 = b_ih[64 + ch0] + b_hh[64 + ch0], bz1 = b_ih[64 + ch1] + b_hh[64 + ch1];
  const float bi0 = b_ih[128 + ch0], bi1 = b_ih[128 + ch1];
  const float bn0 = b_hh[128 + ch0], bn1 = b_hh[128 + ch1];

  const int g = tid >> 3, qc = tid & 7;   // staging: node-in-tile, ch-octet

  for (int tile = blockIdx.x; tile < ntiles; tile += gridDim.x) {
    const int nb = tile * 64;
    const int node = nb + g;
    {  // ---- s staging: raw bf16 copy ----
      uint4 sv = make_uint4(0, 0, 0, 0);
      if (node < N) sv = *(const uint4*)(s16 + (size_t)node * 64 + qc * 8);
      *(uint4*)&Ahi[g * HSTR + qc * 8] = sv;
    }
    {  // ---- h staging: hi/lo split, 8 ch ----
      f32x4 v0 = (f32x4)(0.f), v1 = (f32x4)(0.f);
      if (node < N) {
        v0 = *(const f32x4*)(hin + (size_t)node * 64 + qc * 8);
        v1 = *(const f32x4*)(hin + (size_t)node * 64 + qc * 8 + 4);
      }
      s8v hv, lv;
#pragma unroll
      for (int i = 0; i < 8; i++) {
        float x = (i < 4) ? v0[i] : v1[i - 4];
        unsigned short hb = f32_bf16_rn(x);
        hv[i] = (short)hb;
        lv[i] = (short)f32_bf16_rn(x - __uint_as_float((unsigned)hb << 16));
      }
      *(s8v*)&Ahi[g * HSTR + 64 + qc * 8] = hv;
      *(s8v*)&Alo[g * LSTR + qc * 8] = lv;
    }
    __syncthreads();

    f32x4 acc[4][2];
#pragma unroll
    for (int m = 0; m < 4; m++)
#pragma unroll
      for (int ct = 0; ct < 2; ct++) acc[m][ct] = (f32x4)(0.f);

#pragma unroll
    for (int m = 0; m < 4; m++) {
      const short* arh = &Ahi[(16 * m + l15) * HSTR + ko];
      const short* arl = &Alo[(16 * m + l15) * LSTR + ko];
#pragma unroll
      for (int kk = 0; kk < 4; kk++) {
        s8v a_h = *(const s8v*)(arh + kk * 32);
#pragma unroll
        for (int ct = 0; ct < 2; ct++)   // SWAPPED operands: W is arg0
          acc[m][ct] = __builtin_amdgcn_mfma_f32_16x16x32_bf16(Bf[ct][kk], a_h, acc[m][ct], 0, 0, 0);
        if (kk >= 2) {
          s8v a_l = *(const s8v*)(arl + (kk - 2) * 32);
#pragma unroll
          for (int ct = 0; ct < 2; ct++)
            acc[m][ct] = __builtin_amdgcn_mfma_f32_16x16x32_bf16(Bf[ct][kk], a_l, acc[m][ct], 0, 0, 0);
        }
      }
    }

    // ---- GRU gate epilogue: fully lane-parallel, acc = (r,z,in,hn) ----
#pragma unroll
    for (int m = 0; m < 4; m++) {
      int loc = 16 * m + l15;
      int nd = nb + loc;
      if (nd < N) {
#pragma unroll
        for (int ct = 0; ct < 2; ct++) {
          int ch = ct ? ch1 : ch0;
          unsigned hi = (unsigned short)Ahi[loc * HSTR + 64 + ch];
          unsigned lo = (unsigned short)Alo[loc * LSTR + ch];
          float hold = __uint_as_float(hi << 16) + __uint_as_float(lo << 16);
          float rr = 1.f / (1.f + __expf(-(acc[m][ct][0] + (ct ? br1 : br0))));
          float zz = 1.f / (1.f + __expf(-(acc[m][ct][1] + (ct ? bz1 : bz0))));
          float narg = acc[m][ct][2] + (ct ? bi1 : bi0) +
                       rr * (acc[m][ct][3] + (ct ? bn1 : bn0));
          narg = fminf(fmaxf(narg, -15.f), 15.f);
          float t = __expf(2.f * narg);
          float nn = (t - 1.f) / (t + 1.f);
          float hv = (1.f - zz) * nn + zz * hold;
          hout[(size_t)nd * 64 + ch] = hv;
          if (wb16) hb16[(size_t)nd * 64 + ch] = f32_bf16_rn(hv);
        }
      }
    }
    __syncthreads();  // LDS (epilogue reads) safe before next staging
  }
}

// Readout via MFMA: y = relu(h)@lin_w^T + lin_b; t = y.attn_w + attn_b;
// softmax-attention partial sums accumulated in registers across tiles.
__global__ __launch_bounds__(256, 2) void final_mfma(
    const float* __restrict__ h, const unsigned short* __restrict__ Lt,
    const float* __restrict__ lin_b, const float* __restrict__ attn_w,
    const float* __restrict__ attn_b, float* __restrict__ partials,
    int N, int ntiles) {
  __shared__ short Alds[2 * 64 * 72];   // hi then lo, stride 72 shorts
  __shared__ float red[4][64];
  __shared__ float pl[64];
  const int tid = threadIdx.x;
  const int lane = tid & 63, w = tid >> 6;
  const int l15 = lane & 15, ko = (lane >> 4) * 8;
  const int q = lane >> 4;

  s8v Lh[2], Ll[2];
  const int col = 16 * w + l15;
#pragma unroll
  for (int kk = 0; kk < 2; kk++) {
    Lh[kk] = *(const s8v*)(Lt + (size_t)col * 64 + kk * 32 + ko);
    Ll[kk] = *(const s8v*)(Lt + 4096 + (size_t)col * 64 + kk * 32 + ko);
  }
  const float lb = lin_b[col];
  const float aw = attn_w[col];
  const float ab = attn_b[0];
  const int sr = tid >> 2, part = tid & 3;

  float accS = 0.f;
  float accY = 0.f;

  for (int tile = blockIdx.x; tile < ntiles; tile += gridDim.x) {
    const int nb = tile * 64;
    {  // ---- stage relu(h) as bf16 hi/lo ----
      int node = nb + sr;
      f32x4 v[4];
      if (node < N) {
#pragma unroll
        for (int i = 0; i < 4; i++)
          v[i] = *(const f32x4*)(h + (size_t)node * 64 + part * 16 + 4 * i);
      } else {
#pragma unroll
        for (int i = 0; i < 4; i++) v[i] = (f32x4)(0.f);
      }
      short* ah = &Alds[sr * 72 + part * 16];
#pragma unroll
      for (int i2 = 0; i2 < 2; i2++) {
        s8v hv, lv;
#pragma unroll
        for (int e = 0; e < 8; e++) {
          float x = fmaxf(v[i2 * 2 + (e >> 2)][e & 3], 0.f);
          unsigned short hb = f32_bf16_rn(x);
          float fh = __uint_as_float((unsigned)hb << 16);
          unsigned short lo2 = f32_bf16_rn(x - fh);
          hv[e] = (short)hb;
          lv[e] = (short)lo2;
        }
        *(s8v*)(ah + i2 * 8) = hv;
        *(s8v*)(ah + 64 * 72 + i2 * 8) = lv;
      }
    }
    __syncthreads();

    f32x4 acc[4];
#pragma unroll
    for (int m = 0; m < 4; m++) acc[m] = (f32x4)(0.f);
#pragma unroll
    for (int m = 0; m < 4; m++) {
      const short* arow = &Alds[(16 * m + l15) * 72 + ko];
#pragma unroll
      for (int kk = 0; kk < 2; kk++) {
        s8v a_h = *(const s8v*)(arow + kk * 32);
        s8v a_l = *(const s8v*)(arow + 64 * 72 + kk * 32);
        acc[m] = __builtin_amdgcn_mfma_f32_16x16x32_bf16(a_h, Lh[kk], acc[m], 0, 0, 0);
        acc[m] = __builtin_amdgcn_mfma_f32_16x16x32_bf16(a_h, Ll[kk], acc[m], 0, 0, 0);
        acc[m] = __builtin_amdgcn_mfma_f32_16x16x32_bf16(a_l, Lh[kk], acc[m], 0, 0, 0);
      }
    }
    __syncthreads();

    float cc[4][4];
#pragma unroll
    for (int m = 0; m < 4; m++)
#pragma unroll
      for (int g = 0; g < 4; g++) cc[m][g] = (acc[m][g] + lb) * aw;
#pragma unroll
    for (int off = 1; off <= 8; off <<= 1)
#pragma unroll
      for (int m = 0; m < 4; m++)
#pragma unroll
        for (int g = 0; g < 4; g++) cc[m][g] += __shfl_xor(cc[m][g], off);
    if (l15 == 0) {
#pragma unroll
      for (int m = 0; m < 4; m++)
#pragma unroll
        for (int g = 0; g < 4; g++) red[w][16 * m + 4 * q + g] = cc[m][g];
    }
    __syncthreads();
    if (tid < 64) {
      float t = red[0][tid] + red[1][tid] + red[2][tid] + red[3][tid] + ab;
      float p = (nb + tid < N) ? __expf(t) : 0.f;
      pl[tid] = p;
      accS += p;
    }
    __syncthreads();
#pragma unroll
    for (int m = 0; m < 4; m++)
#pragma unroll
      for (int g = 0; g < 4; g++)
        accY += pl[16 * m + 4 * q + g] * (acc[m][g] + lb);
  }

  accY += __shfl_xor(accY, 16);
  accY += __shfl_xor(accY, 32);
  if (lane < 16) partials[(size_t)blockIdx.x * 66 + 16 * w + lane] = accY;
  if (w == 0) {
    float s = accS;
#pragma unroll
    for (int off = 1; off < 64; off <<= 1) s += __shfl_xor(s, off);
    if (lane == 0) partials[(size_t)blockIdx.x * 66 + 64] = s;
  }
}

__global__ void final_p2(const float* __restrict__ partials,
                         float* __restrict__ out, int nb) {
  __shared__ float red[16][65];
  int tid = threadIdx.x;  // 1024
  int j = tid & 63, grp = tid >> 6;
  float sy = 0.f, ss = 0.f;
  for (int b = grp; b < nb; b += 16) {
    sy += partials[b * 66 + j];
    if (j == 0) ss += partials[b * 66 + 64];
  }
  red[grp][j] = sy;
  if (j == 0) red[grp][64] = ss;
  __syncthreads();
  if (tid < 64) {
    float Y = 0.f, S = 0.f;
#pragma unroll
    for (int i = 0; i < 16; i++) { Y += red[i][tid]; S += red[i][64]; }
    out[tid] = Y / S;
  }
}

extern "C" void kernel_launch(void* const* d_in, const int* in_sizes, int n_in,
                              void* d_out, int out_size, void* d_ws, size_t ws_size,
                              hipStream_t stream) {
  const float* x       = (const float*)d_in[0];
  const int*   ei      = (const int*)d_in[1];
  const float* conv_w  = (const float*)d_in[2];
  const float* gw_ih   = (const float*)d_in[3];
  const float* gw_hh   = (const float*)d_in[4];
  const float* gb_ih   = (const float*)d_in[5];
  const float* gb_hh   = (const float*)d_in[6];
  const float* lin_w   = (const float*)d_in[7];
  const float* lin_b   = (const float*)d_in[8];
  const float* attn_w  = (const float*)d_in[9];
  const float* attn_b  = (const float*)d_in[10];
  float* out = (float*)d_out;

  const int N = in_sizes[0] / 64;
  const int E = in_sizes[1] / 2;
  const int P  = (N + 255) >> 8;   // 256-node partitions
  const int NB = 256;              // binning blocks
  const int perBlk = (E + NB - 1) / NB;

  char* ws = (char*)d_ws;
  size_t off = 0;
  auto alloc = [&](size_t bytes) {
    void* p = ws + off;
    off = (off + bytes + 255) & ~(size_t)255;
    return p;
  };
  int*   G         = (int*)alloc((size_t)P * NB * 4);
  int*   total     = (int*)alloc((size_t)P * 4);
  int*   partStart = (int*)alloc((size_t)(P + 1) * 4);
  int*   bucket    = (int*)alloc((size_t)E * 4);
  int*   row_ptr   = (int*)alloc((size_t)(N + 1) * 4);
  int*   colb      = (int*)alloc((size_t)E * 4);
  unsigned short* Bt  = (unsigned short*)alloc(2 * 256 * 128 * 2);
  unsigned short* Lt  = (unsigned short*)alloc(2 * 4096 * 2);
  unsigned short* b16x = (unsigned short*)alloc((size_t)N * 64 * 2);  // x bf16
  unsigned short* b16h = (unsigned short*)alloc((size_t)N * 64 * 2);  // h1 bf16
  unsigned short* s16  = (unsigned short*)alloc((size_t)N * 64 * 2);  // gathered s
  float* hbuf      = (float*)alloc((size_t)N * 64 * 4);
  float* partials  = (float*)alloc(1024 * 66 * 4);
  if (off > ws_size) return;  // ws too small: leave output poisoned

  count_kernel<<<NB, 256, 0, stream>>>(ei, E, G, P, perBlk, NB);
  scan2a<<<P, 256, 0, stream>>>(G, total, NB);
  scan2b<<<1, 64, 0, stream>>>(total, partStart, P);
  scatter_kernel<<<NB, 256, 0, stream>>>(ei, E, G, partStart, bucket, P, perBlk, NB);
  buildcsr_kernel<<<P, 256, 0, stream>>>(partStart, bucket, row_ptr, colb, N);
  wprep_kernel<<<(65536 + 4096 + 255) / 256, 256, 0, stream>>>(conv_w, gw_ih, gw_hh,
                                                               lin_w, Bt, Lt);
  int n8 = (N * 64) / 8;
  cvt16_kernel<<<(n8 + 255) / 256, 256, 0, stream>>>(x, b16x, n8);

  int gb = (N * 64 + 255) / 256;       // gather: 1 wave per node
  int ntiles = (N + 63) / 64;
  // layer 0: gather from x-bf16; h = x; gemm emits h1 bf16 into b16h
  gather_kernel<<<gb, 256, 0, stream>>>(b16x, row_ptr, colb, s16, N, E - 1);
  gemm_gru_kernel<<<1024, 512, 0, stream>>>(s16, x, hbuf, b16h, Bt,
                                            gb_ih, gb_hh, N, ntiles, 1);
  // layer 1: gather from h1-bf16; h = hbuf (in-place update)
  gather_kernel<<<gb, 256, 0, stream>>>(b16h, row_ptr, colb, s16, N, E - 1);
  gemm_gru_kernel<<<1024, 512, 0, stream>>>(s16, hbuf, hbuf, b16h, Bt + 32768,
                                            gb_ih, gb_hh, N, ntiles, 0);
  // readout
  final_mfma<<<512, 256, 0, stream>>>(hbuf, Lt, lin_b, attn_w, attn_b, partials, N, ntiles);
  final_p2<<<1, 1024, 0, stream>>>(partials, out, 512);
}

// Round 16
// 217.307 us; speedup vs baseline: 1.4883x; 1.0743x over previous
//
#include <hip/hip_runtime.h>

// ---------------------------------------------------------------------------
// GGNN: 2x GatedGraphConv(GRUCell) + linear + softmax-attention pooling.
// N=100000 nodes, E=1600000 edges, D=64.
//
// Folds: segment_sum((h@C)[src]) == (segment_sum(h[src]))@C, and
// agg@W_ih^T == s@(C@W_ih^T).  h lives as SINGLE bf16 end-to-end (s has
// been single-bf16 since R9 at absmax 1.2e-4 vs 3.5e-3 threshold; h's
// per-node rounding error averages out in attention pooling).  Per layer:
// node-parallel register gather of bf16 h rows (8-deep batched loads,
// ~4.4 TB/s effective random-row rate), then a lean MFMA GEMM + GRU kernel
// streaming pure bf16 (staging = raw uint4 copies, 32 MFMA/tile, hold
// reconstructed from staged bf16).
//
// GEMM: operand-SWAPPED MFMA  D = W x Act^T  with gate-interleaved W rows
// (c' = ch*4+gate): each lane's f32x4 acc holds (r,z,i_n,h_n) of ONE
// (node,ch) -> GRU epilogue fully lane-parallel, zero cross-lane ops.
//
// CSR build (atomic-free, locality-clean): count -> scan2a/b -> scatter ->
// buildcsr.  Readout: MFMA tile GEMM with in-register softmax-attention.
// ---------------------------------------------------------------------------

typedef __attribute__((ext_vector_type(8))) short s8v;    // 8 bf16 (4 VGPRs)
typedef __attribute__((ext_vector_type(4))) float f32x4;  // MFMA accumulator

#define CSR_CAP 12288   // per-partition stage capacity (avg cnt ~4090)
#define HSTR 136        // A LDS row stride (shorts): 128 + 8 pad

__device__ __forceinline__ unsigned short f32_bf16_rn(float x) {
  unsigned u = __float_as_uint(x);
  u += 0x7FFF + ((u >> 16) & 1);
  return (unsigned short)(u >> 16);
}

__device__ __forceinline__ int wave_incl_scan(int v, int lane) {
#pragma unroll
  for (int d = 1; d < 64; d <<= 1) {
    int u = __shfl_up(v, d);
    if (lane >= d) v += u;
  }
  return v;
}

// Edge list may arrive as int32 or as int64 (we read low dwords).
__device__ __forceinline__ int detect_is64(const int* ei, int E) {
  int nz = 0;
  int lim = (E < 512) ? E : 512;
  for (int i = threadIdx.x; i < lim; i += blockDim.x)
    nz |= (ei[2 * i + 1] != 0);
  return __syncthreads_or(nz) ? 0 : 1;
}

__device__ __forceinline__ void load_edge(const int* ei, int E, int is64,
                                          int e, int& s, int& d) {
  if (is64) { s = ei[2 * e]; d = ei[2 * (E + e)]; }
  else      { s = ei[e];     d = ei[E + e]; }
}

// ---- pass 1: per-block LDS histogram over partitions (dst>>8) ----
__global__ __launch_bounds__(256) void count_kernel(
    const int* __restrict__ ei, int E,
    int* __restrict__ G, int P, int perBlk, int NB) {
  __shared__ int hist[512];
  int tid = threadIdx.x, b = blockIdx.x;
  for (int i = tid; i < 512; i += 256) hist[i] = 0;
  int is64 = detect_is64(ei, E);
  __syncthreads();
  int e0 = b * perBlk, e1 = min(e0 + perBlk, E);
  for (int e = e0 + tid; e < e1; e += 256) {
    int s, d; load_edge(ei, E, is64, e, s, d);
    atomicAdd(&hist[d >> 8], 1);
  }
  __syncthreads();
  for (int i = tid; i < P; i += 256) G[i * NB + b] = hist[i];
}

// ---- pass 2a: per-partition exclusive scan of per-block counts ----
__global__ __launch_bounds__(256) void scan2a(int* __restrict__ G,
                                              int* __restrict__ total, int NB) {
  __shared__ int wsum[4];
  int p = blockIdx.x, tid = threadIdx.x, lane = tid & 63, wv = tid >> 6;
  int v = G[p * NB + tid];
  int incl = wave_incl_scan(v, lane);
  if (lane == 63) wsum[wv] = incl;
  __syncthreads();
  if (tid == 0) {
    int a = wsum[0], b2 = wsum[1], c = wsum[2], d = wsum[3];
    total[p] = a + b2 + c + d;
    wsum[0] = 0; wsum[1] = a; wsum[2] = a + b2; wsum[3] = a + b2 + c;
  }
  __syncthreads();
  G[p * NB + tid] = incl - v + wsum[wv];
}

// ---- pass 2b: exclusive scan of partition totals -> partStart[P+1] ----
__global__ void scan2b(const int* __restrict__ total, int* __restrict__ partStart,
                       int P) {
  int lane = threadIdx.x;  // 64 threads
  int running = 0;
  for (int base = 0; base < P; base += 64) {
    int idx = base + lane;
    int v = (idx < P) ? total[idx] : 0;
    int incl = wave_incl_scan(v, lane);
    int tot = __shfl(incl, 63);
    if (idx < P) partStart[idx] = running + incl - v;
    running += tot;
  }
  if (lane == 0) partStart[P] = running;
}

// ---- pass 3: scatter packed edges into partition-major bucket ----
__global__ __launch_bounds__(256) void scatter_kernel(
    const int* __restrict__ ei, int E,
    const int* __restrict__ G, const int* __restrict__ partStart,
    int* __restrict__ bucket, int P, int perBlk, int NB) {
  __shared__ int cur[512];
  int tid = threadIdx.x, b = blockIdx.x;
  int is64 = detect_is64(ei, E);
  for (int i = tid; i < P; i += 256) cur[i] = partStart[i] + G[i * NB + b];
  __syncthreads();
  int e0 = b * perBlk, e1 = min(e0 + perBlk, E);
  for (int e = e0 + tid; e < e1; e += 256) {
    int s, d; load_edge(ei, E, is64, e, s, d);
    int pos = atomicAdd(&cur[d >> 8], 1);   // LDS atomic
    bucket[pos] = ((d & 255) << 17) | s;
  }
}

// ---- pass 4: per-partition CSR finalize (row_ptr + node-sorted col) ----
__global__ __launch_bounds__(256) void buildcsr_kernel(
    const int* __restrict__ partStart, const int* __restrict__ bucket,
    int* __restrict__ row_ptr, int* __restrict__ col, int N) {
  __shared__ int stage[CSR_CAP];
  __shared__ int hist[256];
  __shared__ int cur[256];
  __shared__ int wsum[4];
  int p = blockIdx.x, tid = threadIdx.x;
  int beg = partStart[p], end = partStart[p + 1];
  int cnt = end - beg;
  int base = p << 8;
  hist[tid] = 0;
  __syncthreads();
  bool staged = (cnt <= CSR_CAP);
  if (staged) {
    for (int i = tid; i < cnt; i += 256) {
      int v = bucket[beg + i];
      stage[i] = v;
      atomicAdd(&hist[(v >> 17) & 255], 1);
    }
  } else {
    for (int i = tid; i < cnt; i += 256)
      atomicAdd(&hist[(bucket[beg + i] >> 17) & 255], 1);
  }
  __syncthreads();
  int lane = tid & 63, wv = tid >> 6;
  int v = hist[tid];
  int incl = wave_incl_scan(v, lane);
  if (lane == 63) wsum[wv] = incl;
  __syncthreads();
  if (tid == 0) {
    int s0 = wsum[0], s1 = wsum[1], s2 = wsum[2];
    wsum[0] = 0; wsum[1] = s0; wsum[2] = s0 + s1; wsum[3] = s0 + s1 + s2;
  }
  __syncthreads();
  int excl = incl - v + wsum[wv];
  cur[tid] = beg + excl;
  if (base + tid < N) {
    if (tid == 0) row_ptr[base] = beg;
    row_ptr[base + tid + 1] = beg + excl + v;
  }
  __syncthreads();
  if (staged) {
    for (int i = tid; i < cnt; i += 256) {
      int v2 = stage[i];
      int pos = atomicAdd(&cur[(v2 >> 17) & 255], 1);
      col[pos] = v2 & 0x1FFFF;
    }
  } else {
    for (int i = tid; i < cnt; i += 256) {
      int v2 = bucket[beg + i];
      int pos = atomicAdd(&cur[(v2 >> 17) & 255], 1);
      col[pos] = v2 & 0x1FFFF;
    }
  }
}

// ---- weight prep: Bt (gru GEMM B, bf16, gate-interleaved cols c'=ch*4+g)
//      + Lt (lin_w, hi/lo) ----
__global__ void wprep_kernel(const float* __restrict__ conv_w,
                             const float* __restrict__ w_ih,
                             const float* __restrict__ whh,
                             const float* __restrict__ lin_w,
                             unsigned short* __restrict__ Bt,
                             unsigned short* __restrict__ Lt) {
  int idx = blockIdx.x * blockDim.x + threadIdx.x;
  if (idx < 65536) {
    int l = idx >> 15;
    int rr = idx & 32767;
    int cp = rr >> 7, p = rr & 127;
    int ch = cp >> 2, g = cp & 3;
    float val = 0.f;
    if (p < 64) {
      int j = (g == 0) ? ch : (g == 1) ? 64 + ch : (g == 2) ? 128 + ch : -1;
      if (j >= 0) {
        const float* C = conv_w + l * 4096 + p * 64;
        const float* W = w_ih + j * 64;
#pragma unroll 8
        for (int k = 0; k < 64; k++) val += C[k] * W[k];
      }
    } else {
      int q = p - 64;
      if (g == 0)      val = whh[ch * 64 + q];
      else if (g == 1) val = whh[(64 + ch) * 64 + q];
      else if (g == 3) val = whh[(128 + ch) * 64 + q];
    }
    Bt[(size_t)l * 32768 + (size_t)cp * 128 + p] = f32_bf16_rn(val);
  } else if (idx < 65536 + 4096) {
    int i2 = idx - 65536;
    float val = lin_w[i2];
    unsigned short hi = f32_bf16_rn(val);
    float fh = __uint_as_float((unsigned)hi << 16);
    unsigned short lo = f32_bf16_rn(val - fh);
    Lt[i2] = hi;
    Lt[4096 + i2] = lo;
  }
}

// ---- f32 -> bf16 row copy (for the gather source) ----
__global__ __launch_bounds__(256) void cvt16_kernel(
    const float* __restrict__ in, unsigned short* __restrict__ out, int n8) {
  int idx = blockIdx.x * blockDim.x + threadIdx.x;
  if (idx >= n8) return;
  const float4* p = (const float4*)(in + (size_t)idx * 8);
  float4 v0 = p[0], v1 = p[1];
  uint4 o;
  o.x = (unsigned)f32_bf16_rn(v0.x) | ((unsigned)f32_bf16_rn(v0.y) << 16);
  o.y = (unsigned)f32_bf16_rn(v0.z) | ((unsigned)f32_bf16_rn(v0.w) << 16);
  o.z = (unsigned)f32_bf16_rn(v1.x) | ((unsigned)f32_bf16_rn(v1.y) << 16);
  o.w = (unsigned)f32_bf16_rn(v1.z) | ((unsigned)f32_bf16_rn(v1.w) << 16);
  *(uint4*)(out + (size_t)idx * 8) = o;
}

__device__ __forceinline__ void acc_u2(unsigned rx, unsigned ry, float4& a) {
  a.x += __uint_as_float(rx << 16);
  a.y += __uint_as_float(rx & 0xFFFF0000u);
  a.z += __uint_as_float(ry << 16);
  a.w += __uint_as_float(ry & 0xFFFF0000u);
}

// s[n,:] = sum over in-edges of bf16 h[src,:] (f32 accumulate, bf16 out).
// One wave per node; lane = (edge-group 0..3) x (bf16x4 chunk 0..15).
// 8-deep explicit load batch per group (covers degree<=32; mean group
// degree = 4).  Invalid slots re-load the group's first row (L1-hit).
__global__ __launch_bounds__(256) void gather_kernel(
    const unsigned short* __restrict__ hb, const int* __restrict__ row_ptr,
    const int* __restrict__ col, unsigned short* __restrict__ sout,
    int N, int Em1) {
  int gt = blockIdx.x * blockDim.x + threadIdx.x;
  int n = gt >> 6, lane = gt & 63;
  if (n >= N) return;
  int grp = lane >> 4, q = lane & 15;
  int beg = row_ptr[n], end = row_ptr[n + 1];
  float4 acc = make_float4(0.f, 0.f, 0.f, 0.f);

  {  // ---- 8-deep batched head: edges beg+grp+4*i, i in [0,8) ----
    int safe0 = min(beg, Em1);
    uint2 r[8];
    int idx[8];
#pragma unroll
    for (int i = 0; i < 8; i++) {
      int ee = beg + grp + 4 * i;
      idx[i] = (ee < end) ? ee : -1;
      int ci = (idx[i] >= 0) ? ee : safe0;
      int s = col[ci];
      r[i] = *(const uint2*)(hb + (size_t)s * 64 + q * 4);
    }
#pragma unroll
    for (int i = 0; i < 8; i++)
      if (idx[i] >= 0) acc_u2(r[i].x, r[i].y, acc);
  }
  // ---- rare tail: degree > 32 ----
  for (int ee = beg + grp + 32; ee < end; ee += 4) {
    int s = col[ee];
    uint2 r = *(const uint2*)(hb + (size_t)s * 64 + q * 4);
    acc_u2(r.x, r.y, acc);
  }

#pragma unroll
  for (int off = 16; off <= 32; off <<= 1) {
    acc.x += __shfl_xor(acc.x, off);
    acc.y += __shfl_xor(acc.y, off);
    acc.z += __shfl_xor(acc.z, off);
    acc.w += __shfl_xor(acc.w, off);
  }
  if (grp == 0) {
    uint2 o;
    o.x = (unsigned)f32_bf16_rn(acc.x) | ((unsigned)f32_bf16_rn(acc.y) << 16);
    o.y = (unsigned)f32_bf16_rn(acc.z) | ((unsigned)f32_bf16_rn(acc.w) << 16);
    *(uint2*)(sout + (size_t)n * 64 + q * 4) = o;
  }
}

// MFMA GEMM + GRU gates, operand-swapped: D = W x Act^T, pure-bf16 stream.
// 512 threads (8 waves), tile = 64 nodes.  Staging = two raw uint4 copies
// (s row + h row, both bf16).  Wave w owns c' rows [32w,32w+32) x all 4
// node-subtiles; 32 MFMA/tile.  Output: col=node(l15), row=c' -> lane's
// f32x4 acc = (r,z,in,hn) of (node = 16m+l15, ch = 8w+4ct+q).  Epilogue
// lane-parallel; hold reconstructed from staged bf16 h; writes bf16 h.
__global__ __launch_bounds__(512, 4) void gemm_gru_kernel(
    const unsigned short* __restrict__ s16,
    const unsigned short* __restrict__ h16in,
    unsigned short* __restrict__ h16out,
    const unsigned short* __restrict__ bt,
    const float* __restrict__ b_ih, const float* __restrict__ b_hh,
    int N, int ntiles) {
  __shared__ short Ahi[64 * HSTR];   // [s(0:64) || h(64:128)] bf16
  const int tid = threadIdx.x;
  const int lane = tid & 63, w = tid >> 6;
  const int l15 = lane & 15, ko = (lane >> 4) * 8;
  const int q = lane >> 4;

  // W fragments (A-operand of swapped MFMA): lane holds W[c'=32w+16ct+l15][k].
  s8v Bf[2][4];
#pragma unroll
  for (int ct = 0; ct < 2; ct++)
#pragma unroll
    for (int kk = 0; kk < 4; kk++)
      Bf[ct][kk] = *(const s8v*)(bt + (size_t)(32 * w + 16 * ct + l15) * 128 +
                                 kk * 32 + ko);

  // This lane's channels: ct=0 -> 8w+q, ct=1 -> 8w+4+q.
  const int ch0 = 8 * w + q, ch1 = ch0 + 4;
  const float br0 = b_ih[ch0] + b_hh[ch0], br1 = b_ih[ch1] + b_hh[ch1];
  const float bz0 = b_ih[64 + ch0] + b_hh[64 + ch0], bz1 = b_ih[64 + ch1] + b_hh[64 + ch1];
  const float bi0 = b_ih[128 + ch0], bi1 = b_ih[128 + ch1];
  const float bn0 = b_hh[128 + ch0], bn1 = b_hh[128 + ch1];

  const int g = tid >> 3, qc = tid & 7;   // staging: node-in-tile, ch-octet

  for (int tile = blockIdx.x; tile < ntiles; tile += gridDim.x) {
    const int nb = tile * 64;
    const int node = nb + g;
    {  // ---- staging: raw bf16 row copies (s and h) ----
      uint4 sv = make_uint4(0, 0, 0, 0), hv = make_uint4(0, 0, 0, 0);
      if (node < N) {
        sv = *(const uint4*)(s16 + (size_t)node * 64 + qc * 8);
        hv = *(const uint4*)(h16in + (size_t)node * 64 + qc * 8);
      }
      *(uint4*)&Ahi[g * HSTR + qc * 8] = sv;
      *(uint4*)&Ahi[g * HSTR + 64 + qc * 8] = hv;
    }
    __syncthreads();

    f32x4 acc[4][2];
#pragma unroll
    for (int m = 0; m < 4; m++)
#pragma unroll
      for (int ct = 0; ct < 2; ct++) acc[m][ct] = (f32x4)(0.f);

#pragma unroll
    for (int m = 0; m < 4; m++) {
      const short* arh = &Ahi[(16 * m + l15) * HSTR + ko];
#pragma unroll
      for (int kk = 0; kk < 4; kk++) {
        s8v a_h = *(const s8v*)(arh + kk * 32);
#pragma unroll
        for (int ct = 0; ct < 2; ct++)   // SWAPPED operands: W is arg0
          acc[m][ct] = __builtin_amdgcn_mfma_f32_16x16x32_bf16(Bf[ct][kk], a_h, acc[m][ct], 0, 0, 0);
      }
    }

    // ---- GRU gate epilogue: fully lane-parallel, acc = (r,z,in,hn) ----
#pragma unroll
    for (int m = 0; m < 4; m++) {
      int loc = 16 * m + l15;
      int nd = nb + loc;
      if (nd < N) {
#pragma unroll
        for (int ct = 0; ct < 2; ct++) {
          int ch = ct ? ch1 : ch0;
          unsigned hu = (unsigned short)Ahi[loc * HSTR + 64 + ch];
          float hold = __uint_as_float(hu << 16);
          float rr = 1.f / (1.f + __expf(-(acc[m][ct][0] + (ct ? br1 : br0))));
          float zz = 1.f / (1.f + __expf(-(acc[m][ct][1] + (ct ? bz1 : bz0))));
          float narg = acc[m][ct][2] + (ct ? bi1 : bi0) +
                       rr * (acc[m][ct][3] + (ct ? bn1 : bn0));
          narg = fminf(fmaxf(narg, -15.f), 15.f);
          float t = __expf(2.f * narg);
          float nn = (t - 1.f) / (t + 1.f);
          float hv = (1.f - zz) * nn + zz * hold;
          h16out[(size_t)nd * 64 + ch] = f32_bf16_rn(hv);
        }
      }
    }
    __syncthreads();  // LDS (epilogue reads) safe before next staging
  }
}

__device__ __forceinline__ unsigned relu_pk_bf16(unsigned v) {
  unsigned lo = (v & 0x00008000u) ? 0u : (v & 0x0000FFFFu);
  unsigned hi = (v & 0x80000000u) ? 0u : (v & 0xFFFF0000u);
  return lo | hi;
}

// Readout via MFMA: y = relu(h)@lin_w^T + lin_b; t = y.attn_w + attn_b;
// softmax-attention partial sums accumulated in registers across tiles.
// h arrives as bf16; relu = sign-bit mask; A single-term, Lt hi/lo 2-term.
__global__ __launch_bounds__(256, 2) void final_mfma(
    const unsigned short* __restrict__ h16, const unsigned short* __restrict__ Lt,
    const float* __restrict__ lin_b, const float* __restrict__ attn_w,
    const float* __restrict__ attn_b, float* __restrict__ partials,
    int N, int ntiles) {
  __shared__ short Alds[64 * 72];   // relu(h) bf16, stride 72 shorts
  __shared__ float red[4][64];
  __shared__ float pl[64];
  const int tid = threadIdx.x;
  const int lane = tid & 63, w = tid >> 6;
  const int l15 = lane & 15, ko = (lane >> 4) * 8;
  const int q = lane >> 4;

  s8v Lh[2], Ll[2];
  const int col = 16 * w + l15;
#pragma unroll
  for (int kk = 0; kk < 2; kk++) {
    Lh[kk] = *(const s8v*)(Lt + (size_t)col * 64 + kk * 32 + ko);
    Ll[kk] = *(const s8v*)(Lt + 4096 + (size_t)col * 64 + kk * 32 + ko);
  }
  const float lb = lin_b[col];
  const float aw = attn_w[col];
  const float ab = attn_b[0];
  const int sr = tid >> 2, part = tid & 3;

  float accS = 0.f;
  float accY = 0.f;

  for (int tile = blockIdx.x; tile < ntiles; tile += gridDim.x) {
    const int nb = tile * 64;
    {  // ---- stage relu(h) bf16 (sign-bit mask) ----
      int node = nb + sr;
      uint4 v0 = make_uint4(0, 0, 0, 0), v1 = make_uint4(0, 0, 0, 0);
      if (node < N) {
        v0 = *(const uint4*)(h16 + (size_t)node * 64 + part * 16);
        v1 = *(const uint4*)(h16 + (size_t)node * 64 + part * 16 + 8);
      }
      v0.x = relu_pk_bf16(v0.x); v0.y = relu_pk_bf16(v0.y);
      v0.z = relu_pk_bf16(v0.z); v0.w = relu_pk_bf16(v0.w);
      v1.x = relu_pk_bf16(v1.x); v1.y = relu_pk_bf16(v1.y);
      v1.z = relu_pk_bf16(v1.z); v1.w = relu_pk_bf16(v1.w);
      short* ah = &Alds[sr * 72 + part * 16];
      *(uint4*)ah = v0;
      *(uint4*)(ah + 8) = v1;
    }
    __syncthreads();

    f32x4 acc[4];
#pragma unroll
    for (int m = 0; m < 4; m++) acc[m] = (f32x4)(0.f);
#pragma unroll
    for (int m = 0; m < 4; m++) {
      const short* arow = &Alds[(16 * m + l15) * 72 + ko];
#pragma unroll
      for (int kk = 0; kk < 2; kk++) {
        s8v a_h = *(const s8v*)(arow + kk * 32);
        acc[m] = __builtin_amdgcn_mfma_f32_16x16x32_bf16(a_h, Lh[kk], acc[m], 0, 0, 0);
        acc[m] = __builtin_amdgcn_mfma_f32_16x16x32_bf16(a_h, Ll[kk], acc[m], 0, 0, 0);
      }
    }
    __syncthreads();

    float cc[4][4];
#pragma unroll
    for (int m = 0; m < 4; m++)
#pragma unroll
      for (int g = 0; g < 4; g++) cc[m][g] = (acc[m][g] + lb) * aw;
#pragma unroll
    for (int off = 1; off <= 8; off <<= 1)
#pragma unroll
      for (int m = 0; m < 4; m++)
#pragma unroll
        for (int g = 0; g < 4; g++) cc[m][g] += __shfl_xor(cc[m][g], off);
    if (l15 == 0) {
#pragma unroll
      for (int m = 0; m < 4; m++)
#pragma unroll
        for (int g = 0; g < 4; g++) red[w][16 * m + 4 * q + g] = cc[m][g];
    }
    __syncthreads();
    if (tid < 64) {
      float t = red[0][tid] + red[1][tid] + red[2][tid] + red[3][tid] + ab;
      float p = (nb + tid < N) ? __expf(t) : 0.f;
      pl[tid] = p;
      accS += p;
    }
    __syncthreads();
#pragma unroll
    for (int m = 0; m < 4; m++)
#pragma unroll
      for (int g = 0; g < 4; g++)
        accY += pl[16 * m + 4 * q + g] * (acc[m][g] + lb);
  }

  accY += __shfl_xor(accY, 16);
  accY += __shfl_xor(accY, 32);
  if (lane < 16) partials[(size_t)blockIdx.x * 66 + 16 * w + lane] = accY;
  if (w == 0) {
    float s = accS;
#pragma unroll
    for (int off = 1; off < 64; off <<= 1) s += __shfl_xor(s, off);
    if (lane == 0) partials[(size_t)blockIdx.x * 66 + 64] = s;
  }
}

__global__ void final_p2(const float* __restrict__ partials,
                         float* __restrict__ out, int nb) {
  __shared__ float red[16][65];
  int tid = threadIdx.x;  // 1024
  int j = tid & 63, grp = tid >> 6;
  float sy = 0.f, ss = 0.f;
  for (int b = grp; b < nb; b += 16) {
    sy += partials[b * 66 + j];
    if (j == 0) ss += partials[b * 66 + 64];
  }
  red[grp][j] = sy;
  if (j == 0) red[grp][64] = ss;
  __syncthreads();
  if (tid < 64) {
    float Y = 0.f, S = 0.f;
#pragma unroll
    for (int i = 0; i < 16; i++) { Y += red[i][tid]; S += red[i][64]; }
    out[tid] = Y / S;
  }
}

extern "C" void kernel_launch(void* const* d_in, const int* in_sizes, int n_in,
                              void* d_out, int out_size, void* d_ws, size_t ws_size,
                              hipStream_t stream) {
  const float* x       = (const float*)d_in[0];
  const int*   ei      = (const int*)d_in[1];
  const float* conv_w  = (const float*)d_in[2];
  const float* gw_ih   = (const float*)d_in[3];
  const float* gw_hh   = (const float*)d_in[4];
  const float* gb_ih   = (const float*)d_in[5];
  const float* gb_hh   = (const float*)d_in[6];
  const float* lin_w   = (const float*)d_in[7];
  const float* lin_b   = (const float*)d_in[8];
  const float* attn_w  = (const float*)d_in[9];
  const float* attn_b  = (const float*)d_in[10];
  float* out = (float*)d_out;

  const int N = in_sizes[0] / 64;
  const int E = in_sizes[1] / 2;
  const int P  = (N + 255) >> 8;   // 256-node partitions
  const int NB = 256;              // binning blocks
  const int perBlk = (E + NB - 1) / NB;

  char* ws = (char*)d_ws;
  size_t off = 0;
  auto alloc = [&](size_t bytes) {
    void* p = ws + off;
    off = (off + bytes + 255) & ~(size_t)255;
    return p;
  };
  int*   G         = (int*)alloc((size_t)P * NB * 4);
  int*   total     = (int*)alloc((size_t)P * 4);
  int*   partStart = (int*)alloc((size_t)(P + 1) * 4);
  int*   bucket    = (int*)alloc((size_t)E * 4);
  int*   row_ptr   = (int*)alloc((size_t)(N + 1) * 4);
  int*   colb      = (int*)alloc((size_t)E * 4);
  unsigned short* Bt  = (unsigned short*)alloc(2 * 256 * 128 * 2);
  unsigned short* Lt  = (unsigned short*)alloc(2 * 4096 * 2);
  unsigned short* b16x = (unsigned short*)alloc((size_t)N * 64 * 2);  // x bf16
  unsigned short* b16h = (unsigned short*)alloc((size_t)N * 64 * 2);  // h bf16
  unsigned short* s16  = (unsigned short*)alloc((size_t)N * 64 * 2);  // gathered s
  float* partials  = (float*)alloc(1024 * 66 * 4);
  if (off > ws_size) return;  // ws too small: leave output poisoned

  count_kernel<<<NB, 256, 0, stream>>>(ei, E, G, P, perBlk, NB);
  scan2a<<<P, 256, 0, stream>>>(G, total, NB);
  scan2b<<<1, 64, 0, stream>>>(total, partStart, P);
  scatter_kernel<<<NB, 256, 0, stream>>>(ei, E, G, partStart, bucket, P, perBlk, NB);
  buildcsr_kernel<<<P, 256, 0, stream>>>(partStart, bucket, row_ptr, colb, N);
  wprep_kernel<<<(65536 + 4096 + 255) / 256, 256, 0, stream>>>(conv_w, gw_ih, gw_hh,
                                                               lin_w, Bt, Lt);
  int n8 = (N * 64) / 8;
  cvt16_kernel<<<(n8 + 255) / 256, 256, 0, stream>>>(x, b16x, n8);

  int gb = (N * 64 + 255) / 256;       // gather: 1 wave per node
  int ntiles = (N + 63) / 64;
  // layer 0: gather from x-bf16; h_in = x-bf16; writes h1 -> b16h
  gather_kernel<<<gb, 256, 0, stream>>>(b16x, row_ptr, colb, s16, N, E - 1);
  gemm_gru_kernel<<<1024, 512, 0, stream>>>(s16, b16x, b16h, Bt,
                                            gb_ih, gb_hh, N, ntiles);
  // layer 1: gather from h1; in-place h update on b16h (tile-private rows)
  gather_kernel<<<gb, 256, 0, stream>>>(b16h, row_ptr, colb, s16, N, E - 1);
  gemm_gru_kernel<<<1024, 512, 0, stream>>>(s16, b16h, b16h, Bt + 32768,
                                            gb_ih, gb_hh, N, ntiles);
  // readout
  final_mfma<<<512, 256, 0, stream>>>(b16h, Lt, lin_b, attn_w, attn_b, partials, N, ntiles);
  final_p2<<<1, 1024, 0, stream>>>(partials, out, 512);
}